// Round 6
// baseline (172.329 us; speedup 1.0000x reference)
//
#include <hip/hip_runtime.h>

#define N_NODES 100000
#define E_EDGES 1600000
#define IN_DIM  256
#define OUT_DIM 64
#define SLOPE   0.1f

#define BKT_SHIFT  7
#define BKT_NODES  128
#define NBKT       ((N_NODES + BKT_NODES - 1) / BKT_NODES)   // 782
#define BUCKET_CAP 3072
#define SC_BLOCK   1024
#define SC_EPT     16
#define SC_EDGES   (SC_BLOCK * SC_EPT)                        // 16384
#define SC_GRID    ((E_EDGES + SC_EDGES - 1) / SC_EDGES)      // 98
#define HIST_GRID  1024

typedef __attribute__((ext_vector_type(8))) short bhalf8;
typedef __attribute__((ext_vector_type(4))) float f32x4;

__device__ __forceinline__ unsigned short f2bf(float x) {
  unsigned u = __float_as_uint(x);
  u = (u + 0x7fffu + ((u >> 16) & 1u)) >> 16;   // RNE
  return (unsigned short)u;
}

// ---------------- K0: zero bucket counters + detect int32/int64 edge layout ----------------
__global__ void zero_detect_kernel(int* __restrict__ bcnt, const int* __restrict__ edges,
                                   int* __restrict__ flag) {
  int i = blockIdx.x * blockDim.x + threadIdx.x;
  if (i < NBKT) bcnt[i] = 0;
  if (i == 0) {
    int all0 = 1;
    for (int j = 0; j < 64; ++j)
      if (edges[2 * j + 1] != 0) all0 = 0;
    *flag = all0;  // 1 => int64 layout (high dwords zero), 0 => int32
  }
}

// ---------------- K1: emb = bf16(X@W^T)+b via MFMA; A global->reg 2-batch pipeline ------
// 782 blocks x 256 thr (4 waves). W bf16 in LDS (32KB, swizzled). Wave owns 32 rows.
// Two register batches (pa,pb): convert batch KS, immediately re-load its regs with
// KS+2 -> 8 loads in flight, wait is vmcnt(4) not 0.
__device__ __forceinline__ void cvt_af(const float4& r0, const float4& r1, bhalf8& af) {
  af[0] = f2bf(r0.x); af[1] = f2bf(r0.y); af[2] = f2bf(r0.z); af[3] = f2bf(r0.w);
  af[4] = f2bf(r1.x); af[5] = f2bf(r1.y); af[6] = f2bf(r1.z); af[7] = f2bf(r1.w);
}

template<int KS>
__device__ __forceinline__ void gemm_step(float4 (&P)[2][2], const float* const (&arow)[2],
                                          const short* __restrict__ Wlds,
                                          int lg, int lr, int ksw, f32x4 (&acc)[2][4]) {
  bhalf8 af[2];
  #pragma unroll
  for (int rt = 0; rt < 2; ++rt) cvt_af(P[rt][0], P[rt][1], af[rt]);
  if constexpr (KS + 2 < 8) {           // buffer freed -> prefetch KS+2
    #pragma unroll
    for (int rt = 0; rt < 2; ++rt) {
      P[rt][0] = *(const float4*)(arow[rt] + (KS + 2) * 32);
      P[rt][1] = *(const float4*)(arow[rt] + (KS + 2) * 32 + 4);
    }
  }
  bhalf8 bf[4];
  #pragma unroll
  for (int ct = 0; ct < 4; ++ct) {
    const int col_l = ct * 16 + lr;
    bf[ct] = *(const bhalf8*)((const char*)Wlds + col_l * 512 + ((lg * 16 + KS * 64) ^ ksw));
  }
  #pragma unroll
  for (int rt = 0; rt < 2; ++rt)
    #pragma unroll
    for (int ct = 0; ct < 4; ++ct)
      acc[rt][ct] = __builtin_amdgcn_mfma_f32_16x16x32_bf16(af[rt], bf[ct], acc[rt][ct], 0, 0, 0);
}

__global__ __launch_bounds__(256) void embed_kernel(
    const float* __restrict__ features, const float* __restrict__ W,
    const float* __restrict__ bias, const float* __restrict__ a,
    float* __restrict__ emb, float* __restrict__ s1, float* __restrict__ s2)
{
  __shared__ short Wlds[64 * 256];    // 32 KB, col stride 512 B, byte^((col&7)<<4)

  const int t = threadIdx.x;
  const int w = t >> 6;
  const int l = t & 63;
  const int lg = l >> 4;      // 0..3  (k-chunk group)
  const int lr = l & 15;      // 0..15 (row/col within tile)
  const int row0 = blockIdx.x * 128;

  // ---- stage W: thread t -> col=t>>2, k-quarter=(t&3)*64 floats ----
  {
    const int col = t >> 2;
    const int kq  = (t & 3) * 64;
    const float* src = &W[(size_t)col * IN_DIM + kq];
    char* dstbase = (char*)Wlds + col * 512;
    #pragma unroll
    for (int j = 0; j < 8; ++j) {
      const float4 f0 = *(const float4*)&src[j * 8];
      const float4 f1 = *(const float4*)&src[j * 8 + 4];
      bhalf8 v;
      v[0] = f2bf(f0.x); v[1] = f2bf(f0.y); v[2] = f2bf(f0.z); v[3] = f2bf(f0.w);
      v[4] = f2bf(f1.x); v[5] = f2bf(f1.y); v[6] = f2bf(f1.z); v[7] = f2bf(f1.w);
      *(bhalf8*)(dstbase + (((kq * 2 + j * 16)) ^ ((col & 7) << 4))) = v;
    }
  }

  // ---- A fragment base pointers (lane-private rows, clamped for tail block) ----
  const float* arow[2];
  #pragma unroll
  for (int rt = 0; rt < 2; ++rt) {
    const int rowc = min(row0 + w * 32 + rt * 16 + lr, N_NODES - 1);
    arow[rt] = &features[(size_t)rowc * IN_DIM + lg * 8];
  }

  // prologue: batch A <- ks0, batch B <- ks1 (8 loads in flight before any wait)
  float4 pa[2][2], pb[2][2];
  #pragma unroll
  for (int rt = 0; rt < 2; ++rt) {
    pa[rt][0] = *(const float4*)(arow[rt]);
    pa[rt][1] = *(const float4*)(arow[rt] + 4);
    pb[rt][0] = *(const float4*)(arow[rt] + 32);
    pb[rt][1] = *(const float4*)(arow[rt] + 36);
  }

  // ---- acc init with bias ----
  float bc[4];
  #pragma unroll
  for (int ct = 0; ct < 4; ++ct) bc[ct] = bias[ct * 16 + lr];
  f32x4 acc[2][4];
  #pragma unroll
  for (int rt = 0; rt < 2; ++rt)
    #pragma unroll
    for (int ct = 0; ct < 4; ++ct) {
      acc[rt][ct][0] = bc[ct]; acc[rt][ct][1] = bc[ct];
      acc[rt][ct][2] = bc[ct]; acc[rt][ct][3] = bc[ct];
    }

  __syncthreads();   // W staged

  const int ksw = (lr & 7) << 4;
  gemm_step<0>(pa, arow, Wlds, lg, lr, ksw, acc);
  gemm_step<1>(pb, arow, Wlds, lg, lr, ksw, acc);
  gemm_step<2>(pa, arow, Wlds, lg, lr, ksw, acc);
  gemm_step<3>(pb, arow, Wlds, lg, lr, ksw, acc);
  gemm_step<4>(pa, arow, Wlds, lg, lr, ksw, acc);
  gemm_step<5>(pb, arow, Wlds, lg, lr, ksw, acc);
  gemm_step<6>(pa, arow, Wlds, lg, lr, ksw, acc);
  gemm_step<7>(pb, arow, Wlds, lg, lr, ksw, acc);

  // ---- epilogue: emb writes + fused s1/s2 (row dots with a1,a2) ----
  float a1c[4], a2c[4];
  #pragma unroll
  for (int ct = 0; ct < 4; ++ct) {
    a1c[ct] = a[ct * 16 + lr];
    a2c[ct] = a[OUT_DIM + ct * 16 + lr];
  }
  #pragma unroll
  for (int rt = 0; rt < 2; ++rt) {
    #pragma unroll
    for (int i = 0; i < 4; ++i) {
      const int row = row0 + w * 32 + rt * 16 + lg * 4 + i;
      float p1 = 0.f, p2 = 0.f;
      #pragma unroll
      for (int ct = 0; ct < 4; ++ct) {
        const float e = acc[rt][ct][i];
        p1 += e * a1c[ct];
        p2 += e * a2c[ct];
        if (row < N_NODES) emb[(size_t)row * OUT_DIM + ct * 16 + lr] = e;
      }
      #pragma unroll
      for (int o = 1; o < 16; o <<= 1) {
        p1 += __shfl_xor(p1, o, 64);
        p2 += __shfl_xor(p2, o, 64);
      }
      if (lr == 0 && row < N_NODES) { s1[row] = p1; s2[row] = p2; }
    }
  }
}

// ---------------- K1c: bucket histogram (grid-stride, LDS-staged) ----------------
__global__ __launch_bounds__(256) void hist_kernel(const int* __restrict__ edges,
                                                   const int* __restrict__ flag,
                                                   int* __restrict__ bcnt) {
  __shared__ int lh[NBKT];
  const int t = threadIdx.x;
  for (int j = t; j < NBKT; j += 256) lh[j] = 0;
  __syncthreads();
  const int is64 = *flag;
  for (int e = blockIdx.x * 256 + t; e < E_EDGES; e += HIST_GRID * 256) {
    const int s = is64 ? ((const int4*)edges)[e].x : ((const int2*)edges)[e].x;
    atomicAdd(&lh[s >> BKT_SHIFT], 1);
  }
  __syncthreads();
  for (int j = t; j < NBKT; j += 256)
    if (lh[j]) atomicAdd(&bcnt[j], lh[j]);
}

// ---------------- K2: exclusive scan of bucket counts (single block) ----------------
__global__ __launch_bounds__(1024) void bucket_scan_kernel(const int* __restrict__ bcnt,
                                                           int* __restrict__ bbase,
                                                           int* __restrict__ bcur) {
  __shared__ int buf[1024];
  const int t = threadIdx.x;
  const int v = (t < NBKT) ? bcnt[t] : 0;
  buf[t] = v;
  __syncthreads();
  for (int o = 1; o < 1024; o <<= 1) {
    int add = (t >= o) ? buf[t - o] : 0;
    __syncthreads();
    buf[t] += add;
    __syncthreads();
  }
  if (t < NBKT) {
    const int ex = buf[t] - v;
    bbase[t] = ex;
    bcur[t]  = ex;
  }
  if (t == 0) bbase[NBKT] = E_EDGES;
}

// ---------------- K3: bucket scatter (single pass, edges cached in VGPRs) ----------------
__global__ __launch_bounds__(SC_BLOCK) void bucket_scatter_kernel(
    const int* __restrict__ edges, int* __restrict__ bcur,
    int2* __restrict__ pairs, const int* __restrict__ flag)
{
  __shared__ int lh[NBKT];
  __shared__ int lbase[NBKT];
  const int t = threadIdx.x;
  for (int j = t; j < NBKT; j += SC_BLOCK) lh[j] = 0;
  __syncthreads();

  const int is64 = *flag;
  const int e0 = blockIdx.x * SC_EDGES;
  int ss[SC_EPT], dd[SC_EPT];
  #pragma unroll
  for (int i = 0; i < SC_EPT; ++i) {
    const int e = e0 + t + i * SC_BLOCK;
    int s = -1, d = 0;
    if (e < E_EDGES) {
      if (is64) { int4 v = ((const int4*)edges)[e]; s = v.x; d = v.z; }
      else      { int2 v = ((const int2*)edges)[e]; s = v.x; d = v.y; }
      atomicAdd(&lh[s >> BKT_SHIFT], 1);
    }
    ss[i] = s; dd[i] = d;
  }
  __syncthreads();
  for (int j = t; j < NBKT; j += SC_BLOCK) {
    const int c = lh[j];
    lbase[j] = c ? atomicAdd(&bcur[j], c) : 0;
  }
  __syncthreads();
  for (int j = t; j < NBKT; j += SC_BLOCK) lh[j] = 0;
  __syncthreads();
  #pragma unroll
  for (int i = 0; i < SC_EPT; ++i) {
    const int s = ss[i];
    if (s >= 0) {
      const int b = s >> BKT_SHIFT;
      const int pos = lbase[b] + atomicAdd(&lh[b], 1);
      pairs[pos] = make_int2(s, dd[i]);
    }
  }
}

// ---------------- K4: per-bucket counting sort + weight precompute (in place) --------
__global__ __launch_bounds__(256) void bucket_sort_kernel(
    const float* __restrict__ s1, const float* __restrict__ s2,
    const int* __restrict__ bbase, int2* __restrict__ pairs, int* __restrict__ off)
{
  __shared__ int2  lp[BUCKET_CAP];
  __shared__ int   hist[BKT_NODES];
  __shared__ int   loff[BKT_NODES];
  __shared__ float ls1[BKT_NODES];
  const int b = blockIdx.x, t = threadIdx.x;
  const int nbase = b << BKT_SHIFT;
  const int nn = min(BKT_NODES, N_NODES - nbase);
  const int beg = bbase[b], end = bbase[b + 1];
  const int cnt = min(end - beg, BUCKET_CAP);

  if (t < BKT_NODES) {
    hist[t] = 0;
    if (t < nn) ls1[t] = s1[nbase + t];
  }
  __syncthreads();
  for (int j = t; j < cnt; j += 256) {
    const int2 p = pairs[beg + j];
    lp[j] = p;
    atomicAdd(&hist[p.x - nbase], 1);
  }
  __syncthreads();
  if (t < BKT_NODES) loff[t] = hist[t];
  __syncthreads();
  for (int o = 1; o < BKT_NODES; o <<= 1) {
    int add = 0;
    if (t < BKT_NODES && t >= o) add = loff[t - o];
    __syncthreads();
    if (t < BKT_NODES) loff[t] += add;
    __syncthreads();
  }
  int excl = 0;
  if (t < BKT_NODES) {
    excl = loff[t] - hist[t];
    if (t < nn) off[nbase + t] = beg + excl;
  }
  if (b == NBKT - 1 && t == 0) off[N_NODES] = E_EDGES;
  __syncthreads();
  if (t < BKT_NODES) { loff[t] = excl; hist[t] = 0; }
  __syncthreads();
  for (int j = t; j < cnt; j += 256) {
    const int2 p = lp[j];
    const int li = p.x - nbase;
    const int pos = beg + loff[li] + atomicAdd(&hist[li], 1);
    const float lg = ls1[li] + s2[p.y];
    const float w = __expf(lg >= 0.f ? lg : SLOPE * lg);
    pairs[pos] = make_int2(p.y, __float_as_int(w));
  }
}

// ---------------- K5: one wave per node; LDS-broadcast of (dst,w); 8 gathers in flight ---
__global__ __launch_bounds__(256) void aggregate_kernel(
    const float* __restrict__ emb, const float* __restrict__ s1, const float* __restrict__ s2,
    const int* __restrict__ off, const int2* __restrict__ pairs, float* __restrict__ out)
{
  __shared__ int2 buf[4][64];
  const int lane = threadIdx.x & 63;
  const int wv   = threadIdx.x >> 6;
  const int node = blockIdx.x * 4 + wv;
  if (node >= N_NODES) return;

  const float esel = emb[(size_t)node * OUT_DIM + lane];
  const float lgs = s1[node] + s2[node];
  const float wself = __expf(lgs >= 0.f ? lgs : SLOPE * lgs);
  float acc0 = wself * esel, acc1 = 0.f, acc2 = 0.f, acc3 = 0.f;
  float ws0 = wself, ws1 = 0.f;

  const int beg = off[node], end = off[node + 1];
  for (int j0 = beg; j0 < end; j0 += 64) {
    const int idx = j0 + lane;
    buf[wv][lane] = (idx < end) ? pairs[idx] : make_int2(0, 0);  // w=0 pads
    const int m = min(64, end - j0);
    for (int q = 0; q < m; q += 8) {
      const int4 A = *(const int4*)&buf[wv][q];       // (d0,w0,d1,w1) broadcast read
      const int4 B = *(const int4*)&buf[wv][q + 2];
      const int4 C = *(const int4*)&buf[wv][q + 4];
      const int4 D = *(const int4*)&buf[wv][q + 6];
      const float e0 = emb[(size_t)A.x * OUT_DIM + lane];
      const float e1 = emb[(size_t)A.z * OUT_DIM + lane];
      const float e2 = emb[(size_t)B.x * OUT_DIM + lane];
      const float e3 = emb[(size_t)B.z * OUT_DIM + lane];
      const float e4 = emb[(size_t)C.x * OUT_DIM + lane];
      const float e5 = emb[(size_t)C.z * OUT_DIM + lane];
      const float e6 = emb[(size_t)D.x * OUT_DIM + lane];
      const float e7 = emb[(size_t)D.z * OUT_DIM + lane];
      const float w0 = __int_as_float(A.y), w1 = __int_as_float(A.w);
      const float w2 = __int_as_float(B.y), w3 = __int_as_float(B.w);
      const float w4 = __int_as_float(C.y), w5 = __int_as_float(C.w);
      const float w6 = __int_as_float(D.y), w7 = __int_as_float(D.w);
      acc0 += w0 * e0; acc1 += w1 * e1; acc2 += w2 * e2; acc3 += w3 * e3;
      acc0 += w4 * e4; acc1 += w5 * e5; acc2 += w6 * e6; acc3 += w7 * e7;
      ws0 += w0 + w1 + w2 + w3;
      ws1 += w4 + w5 + w6 + w7;
    }
  }
  out[(size_t)node * OUT_DIM + lane] = (acc0 + acc1 + acc2 + acc3) / (ws0 + ws1);
}

extern "C" void kernel_launch(void* const* d_in, const int* in_sizes, int n_in,
                              void* d_out, int out_size, void* d_ws, size_t ws_size,
                              hipStream_t stream) {
  const float* features = (const float*)d_in[0];
  const float* W        = (const float*)d_in[1];
  const float* b        = (const float*)d_in[2];
  const float* a        = (const float*)d_in[3];
  const int*   edges    = (const int*)d_in[4];
  float* out = (float*)d_out;

  // workspace layout (4B units)
  float* emb   = (float*)d_ws;                       // N*64
  float* s1    = emb + (size_t)N_NODES * OUT_DIM;    // N
  float* s2    = s1 + N_NODES;                       // N
  int*   off   = (int*)(s2 + N_NODES);               // N+1
  int*   bcnt  = off + N_NODES + 1;                  // NBKT
  int*   bbase = bcnt + NBKT;                        // NBKT+1
  int*   bcur  = bbase + NBKT + 1;                   // NBKT
  int*   flag  = bcur + NBKT;                        // 1 (+pad)
  int2*  pairs = (int2*)(flag + 8);                  // E (8B each)

  hipLaunchKernelGGL(zero_detect_kernel, dim3((NBKT + 255) / 256), dim3(256), 0, stream,
                     bcnt, edges, flag);
  hipLaunchKernelGGL(embed_kernel, dim3(NBKT), dim3(256), 0, stream,
                     features, W, b, a, emb, s1, s2);
  hipLaunchKernelGGL(hist_kernel, dim3(HIST_GRID), dim3(256), 0, stream,
                     edges, flag, bcnt);
  hipLaunchKernelGGL(bucket_scan_kernel, dim3(1), dim3(1024), 0, stream,
                     bcnt, bbase, bcur);
  hipLaunchKernelGGL(bucket_scatter_kernel, dim3(SC_GRID), dim3(SC_BLOCK), 0, stream,
                     edges, bcur, pairs, flag);
  hipLaunchKernelGGL(bucket_sort_kernel, dim3(NBKT), dim3(256), 0, stream,
                     s1, s2, bbase, pairs, off);
  hipLaunchKernelGGL(aggregate_kernel, dim3((N_NODES + 3) / 4), dim3(256), 0, stream,
                     emb, s1, s2, off, pairs, out);
}

// Round 7
// 152.215 us; speedup vs baseline: 1.1321x; 1.1321x over previous
//
#include <hip/hip_runtime.h>

#define N_NODES 100000
#define E_EDGES 1600000
#define IN_DIM  256
#define OUT_DIM 64
#define SLOPE   0.1f

#define BKT_SHIFT  7
#define BKT_NODES  128
#define NBKT       ((N_NODES + BKT_NODES - 1) / BKT_NODES)   // 782
#define BUCKET_CAP 3072
#define SC_BLOCK   1024
#define SC_EPT     16
#define SC_EDGES   (SC_BLOCK * SC_EPT)                        // 16384
#define SC_GRID    ((E_EDGES + SC_EDGES - 1) / SC_EDGES)      // 98
#define HIST_GRID  1024

typedef __attribute__((ext_vector_type(8))) short bhalf8;
typedef __attribute__((ext_vector_type(4))) float f32x4;

__device__ __forceinline__ unsigned short f2bf(float x) {
  unsigned u = __float_as_uint(x);
  u = (u + 0x7fffu + ((u >> 16) & 1u)) >> 16;   // RNE
  return (unsigned short)u;
}
__device__ __forceinline__ float bf2f(unsigned short u) {
  return __uint_as_float((unsigned)u << 16);
}

// ---------------- K0: zero bucket counters + detect int32/int64 edge layout ----------------
__global__ void zero_detect_kernel(int* __restrict__ bcnt, const int* __restrict__ edges,
                                   int* __restrict__ flag) {
  int i = blockIdx.x * blockDim.x + threadIdx.x;
  if (i < NBKT) bcnt[i] = 0;
  if (i == 0) {
    int all0 = 1;
    for (int j = 0; j < 64; ++j)
      if (edges[2 * j + 1] != 0) all0 = 0;
    *flag = all0;  // 1 => int64 layout (high dwords zero), 0 => int32
  }
}

// ---------------- K1: emb16 = bf16(X@W^T + b) via MFMA; 4-batch A pipeline --------------
__device__ __forceinline__ void cvt_af(const float4& r0, const float4& r1, bhalf8& af) {
  af[0] = f2bf(r0.x); af[1] = f2bf(r0.y); af[2] = f2bf(r0.z); af[3] = f2bf(r0.w);
  af[4] = f2bf(r1.x); af[5] = f2bf(r1.y); af[6] = f2bf(r1.z); af[7] = f2bf(r1.w);
}

template<int KS>
__device__ __forceinline__ void gemm_step(float4 (&P)[2][2], const float* const (&arow)[2],
                                          const short* __restrict__ Wlds,
                                          int lg, int lr, int ksw, f32x4 (&acc)[2][4]) {
  bhalf8 af[2];
  #pragma unroll
  for (int rt = 0; rt < 2; ++rt) cvt_af(P[rt][0], P[rt][1], af[rt]);
  if constexpr (KS + 4 < 8) {           // buffer freed -> prefetch KS+4
    #pragma unroll
    for (int rt = 0; rt < 2; ++rt) {
      P[rt][0] = *(const float4*)(arow[rt] + (KS + 4) * 32);
      P[rt][1] = *(const float4*)(arow[rt] + (KS + 4) * 32 + 4);
    }
  }
  bhalf8 bf[4];
  #pragma unroll
  for (int ct = 0; ct < 4; ++ct) {
    const int col_l = ct * 16 + lr;
    bf[ct] = *(const bhalf8*)((const char*)Wlds + col_l * 512 + ((lg * 16 + KS * 64) ^ ksw));
  }
  #pragma unroll
  for (int rt = 0; rt < 2; ++rt)
    #pragma unroll
    for (int ct = 0; ct < 4; ++ct)
      acc[rt][ct] = __builtin_amdgcn_mfma_f32_16x16x32_bf16(af[rt], bf[ct], acc[rt][ct], 0, 0, 0);
}

__global__ __launch_bounds__(256) void embed_kernel(
    const float* __restrict__ features, const float* __restrict__ W,
    const float* __restrict__ bias, const float* __restrict__ a,
    unsigned short* __restrict__ emb16, float* __restrict__ s1, float* __restrict__ s2)
{
  __shared__ short Wlds[64 * 256];    // 32 KB, col stride 512 B, byte^((col&7)<<4)

  const int t = threadIdx.x;
  const int w = t >> 6;
  const int l = t & 63;
  const int lg = l >> 4;      // 0..3  (k-chunk group)
  const int lr = l & 15;      // 0..15 (row/col within tile)
  const int row0 = blockIdx.x * 128;

  // ---- stage W: thread t -> col=t>>2, k-quarter=(t&3)*64 floats ----
  {
    const int col = t >> 2;
    const int kq  = (t & 3) * 64;
    const float* src = &W[(size_t)col * IN_DIM + kq];
    char* dstbase = (char*)Wlds + col * 512;
    #pragma unroll
    for (int j = 0; j < 8; ++j) {
      const float4 f0 = *(const float4*)&src[j * 8];
      const float4 f1 = *(const float4*)&src[j * 8 + 4];
      bhalf8 v;
      v[0] = f2bf(f0.x); v[1] = f2bf(f0.y); v[2] = f2bf(f0.z); v[3] = f2bf(f0.w);
      v[4] = f2bf(f1.x); v[5] = f2bf(f1.y); v[6] = f2bf(f1.z); v[7] = f2bf(f1.w);
      *(bhalf8*)(dstbase + (((kq * 2 + j * 16)) ^ ((col & 7) << 4))) = v;
    }
  }

  // ---- A fragment base pointers (lane-private rows, clamped for tail block) ----
  const float* arow[2];
  #pragma unroll
  for (int rt = 0; rt < 2; ++rt) {
    const int rowc = min(row0 + w * 32 + rt * 16 + lr, N_NODES - 1);
    arow[rt] = &features[(size_t)rowc * IN_DIM + lg * 8];
  }

  // prologue: 4 batches <- ks0..ks3 (16 loads in flight before any wait)
  float4 pa[2][2], pb[2][2], pc[2][2], pd[2][2];
  #pragma unroll
  for (int rt = 0; rt < 2; ++rt) {
    pa[rt][0] = *(const float4*)(arow[rt]);
    pa[rt][1] = *(const float4*)(arow[rt] + 4);
    pb[rt][0] = *(const float4*)(arow[rt] + 32);
    pb[rt][1] = *(const float4*)(arow[rt] + 36);
    pc[rt][0] = *(const float4*)(arow[rt] + 64);
    pc[rt][1] = *(const float4*)(arow[rt] + 68);
    pd[rt][0] = *(const float4*)(arow[rt] + 96);
    pd[rt][1] = *(const float4*)(arow[rt] + 100);
  }

  // ---- acc init with bias ----
  float bc[4];
  #pragma unroll
  for (int ct = 0; ct < 4; ++ct) bc[ct] = bias[ct * 16 + lr];
  f32x4 acc[2][4];
  #pragma unroll
  for (int rt = 0; rt < 2; ++rt)
    #pragma unroll
    for (int ct = 0; ct < 4; ++ct) {
      acc[rt][ct][0] = bc[ct]; acc[rt][ct][1] = bc[ct];
      acc[rt][ct][2] = bc[ct]; acc[rt][ct][3] = bc[ct];
    }

  __syncthreads();   // W staged

  const int ksw = (lr & 7) << 4;
  gemm_step<0>(pa, arow, Wlds, lg, lr, ksw, acc);
  gemm_step<1>(pb, arow, Wlds, lg, lr, ksw, acc);
  gemm_step<2>(pc, arow, Wlds, lg, lr, ksw, acc);
  gemm_step<3>(pd, arow, Wlds, lg, lr, ksw, acc);
  gemm_step<4>(pa, arow, Wlds, lg, lr, ksw, acc);
  gemm_step<5>(pb, arow, Wlds, lg, lr, ksw, acc);
  gemm_step<6>(pc, arow, Wlds, lg, lr, ksw, acc);
  gemm_step<7>(pd, arow, Wlds, lg, lr, ksw, acc);

  // ---- epilogue: emb16 writes + fused s1/s2 (row dots with a1,a2) ----
  float a1c[4], a2c[4];
  #pragma unroll
  for (int ct = 0; ct < 4; ++ct) {
    a1c[ct] = a[ct * 16 + lr];
    a2c[ct] = a[OUT_DIM + ct * 16 + lr];
  }
  #pragma unroll
  for (int rt = 0; rt < 2; ++rt) {
    #pragma unroll
    for (int i = 0; i < 4; ++i) {
      const int row = row0 + w * 32 + rt * 16 + lg * 4 + i;
      float p1 = 0.f, p2 = 0.f;
      #pragma unroll
      for (int ct = 0; ct < 4; ++ct) {
        const float e = acc[rt][ct][i];
        p1 += e * a1c[ct];
        p2 += e * a2c[ct];
        if (row < N_NODES) emb16[(size_t)row * OUT_DIM + ct * 16 + lr] = f2bf(e);
      }
      #pragma unroll
      for (int o = 1; o < 16; o <<= 1) {
        p1 += __shfl_xor(p1, o, 64);
        p2 += __shfl_xor(p2, o, 64);
      }
      if (lr == 0 && row < N_NODES) { s1[row] = p1; s2[row] = p2; }
    }
  }
}

// ---------------- K1c: bucket histogram (grid-stride, LDS-staged) ----------------
__global__ __launch_bounds__(256) void hist_kernel(const int* __restrict__ edges,
                                                   const int* __restrict__ flag,
                                                   int* __restrict__ bcnt) {
  __shared__ int lh[NBKT];
  const int t = threadIdx.x;
  for (int j = t; j < NBKT; j += 256) lh[j] = 0;
  __syncthreads();
  const int is64 = *flag;
  for (int e = blockIdx.x * 256 + t; e < E_EDGES; e += HIST_GRID * 256) {
    const int s = is64 ? ((const int4*)edges)[e].x : ((const int2*)edges)[e].x;
    atomicAdd(&lh[s >> BKT_SHIFT], 1);
  }
  __syncthreads();
  for (int j = t; j < NBKT; j += 256)
    if (lh[j]) atomicAdd(&bcnt[j], lh[j]);
}

// ---------------- K2: exclusive scan of bucket counts (single block) ----------------
__global__ __launch_bounds__(1024) void bucket_scan_kernel(const int* __restrict__ bcnt,
                                                           int* __restrict__ bbase,
                                                           int* __restrict__ bcur) {
  __shared__ int buf[1024];
  const int t = threadIdx.x;
  const int v = (t < NBKT) ? bcnt[t] : 0;
  buf[t] = v;
  __syncthreads();
  for (int o = 1; o < 1024; o <<= 1) {
    int add = (t >= o) ? buf[t - o] : 0;
    __syncthreads();
    buf[t] += add;
    __syncthreads();
  }
  if (t < NBKT) {
    const int ex = buf[t] - v;
    bbase[t] = ex;
    bcur[t]  = ex;
  }
  if (t == 0) bbase[NBKT] = E_EDGES;
}

// ---------------- K3: bucket scatter (single pass, edges cached in VGPRs) ----------------
__global__ __launch_bounds__(SC_BLOCK) void bucket_scatter_kernel(
    const int* __restrict__ edges, int* __restrict__ bcur,
    int2* __restrict__ pairs, const int* __restrict__ flag)
{
  __shared__ int lh[NBKT];
  __shared__ int lbase[NBKT];
  const int t = threadIdx.x;
  for (int j = t; j < NBKT; j += SC_BLOCK) lh[j] = 0;
  __syncthreads();

  const int is64 = *flag;
  const int e0 = blockIdx.x * SC_EDGES;
  int ss[SC_EPT], dd[SC_EPT];
  #pragma unroll
  for (int i = 0; i < SC_EPT; ++i) {
    const int e = e0 + t + i * SC_BLOCK;
    int s = -1, d = 0;
    if (e < E_EDGES) {
      if (is64) { int4 v = ((const int4*)edges)[e]; s = v.x; d = v.z; }
      else      { int2 v = ((const int2*)edges)[e]; s = v.x; d = v.y; }
      atomicAdd(&lh[s >> BKT_SHIFT], 1);
    }
    ss[i] = s; dd[i] = d;
  }
  __syncthreads();
  for (int j = t; j < NBKT; j += SC_BLOCK) {
    const int c = lh[j];
    lbase[j] = c ? atomicAdd(&bcur[j], c) : 0;
  }
  __syncthreads();
  for (int j = t; j < NBKT; j += SC_BLOCK) lh[j] = 0;
  __syncthreads();
  #pragma unroll
  for (int i = 0; i < SC_EPT; ++i) {
    const int s = ss[i];
    if (s >= 0) {
      const int b = s >> BKT_SHIFT;
      const int pos = lbase[b] + atomicAdd(&lh[b], 1);
      pairs[pos] = make_int2(s, dd[i]);
    }
  }
}

// ---------------- K4: per-bucket counting sort + weight precompute (in place) --------
__global__ __launch_bounds__(256) void bucket_sort_kernel(
    const float* __restrict__ s1, const float* __restrict__ s2,
    const int* __restrict__ bbase, int2* __restrict__ pairs, int* __restrict__ off)
{
  __shared__ int2  lp[BUCKET_CAP];
  __shared__ int   hist[BKT_NODES];
  __shared__ int   loff[BKT_NODES];
  __shared__ float ls1[BKT_NODES];
  const int b = blockIdx.x, t = threadIdx.x;
  const int nbase = b << BKT_SHIFT;
  const int nn = min(BKT_NODES, N_NODES - nbase);
  const int beg = bbase[b], end = bbase[b + 1];
  const int cnt = min(end - beg, BUCKET_CAP);

  if (t < BKT_NODES) {
    hist[t] = 0;
    if (t < nn) ls1[t] = s1[nbase + t];
  }
  __syncthreads();
  for (int j = t; j < cnt; j += 256) {
    const int2 p = pairs[beg + j];
    lp[j] = p;
    atomicAdd(&hist[p.x - nbase], 1);
  }
  __syncthreads();
  if (t < BKT_NODES) loff[t] = hist[t];
  __syncthreads();
  for (int o = 1; o < BKT_NODES; o <<= 1) {
    int add = 0;
    if (t < BKT_NODES && t >= o) add = loff[t - o];
    __syncthreads();
    if (t < BKT_NODES) loff[t] += add;
    __syncthreads();
  }
  int excl = 0;
  if (t < BKT_NODES) {
    excl = loff[t] - hist[t];
    if (t < nn) off[nbase + t] = beg + excl;
  }
  if (b == NBKT - 1 && t == 0) off[N_NODES] = E_EDGES;
  __syncthreads();
  if (t < BKT_NODES) { loff[t] = excl; hist[t] = 0; }
  __syncthreads();
  for (int j = t; j < cnt; j += 256) {
    const int2 p = lp[j];
    const int li = p.x - nbase;
    const int pos = beg + loff[li] + atomicAdd(&hist[li], 1);
    const float lg = ls1[li] + s2[p.y];
    const float w = __expf(lg >= 0.f ? lg : SLOPE * lg);
    pairs[pos] = make_int2(p.y, __float_as_int(w));
  }
}

// ---------------- K5: one wave per node; LDS-broadcast of (dst,w); bf16 emb gathers -----
__global__ __launch_bounds__(256) void aggregate_kernel(
    const unsigned short* __restrict__ emb16,
    const float* __restrict__ s1, const float* __restrict__ s2,
    const int* __restrict__ off, const int2* __restrict__ pairs, float* __restrict__ out)
{
  __shared__ int2 buf[4][64];
  const int lane = threadIdx.x & 63;
  const int wv   = threadIdx.x >> 6;
  const int node = blockIdx.x * 4 + wv;
  if (node >= N_NODES) return;

  const float esel = bf2f(emb16[(size_t)node * OUT_DIM + lane]);
  const float lgs = s1[node] + s2[node];
  const float wself = __expf(lgs >= 0.f ? lgs : SLOPE * lgs);
  float acc0 = wself * esel, acc1 = 0.f, acc2 = 0.f, acc3 = 0.f;
  float ws0 = wself, ws1 = 0.f;

  const int beg = off[node], end = off[node + 1];
  for (int j0 = beg; j0 < end; j0 += 64) {
    const int idx = j0 + lane;
    buf[wv][lane] = (idx < end) ? pairs[idx] : make_int2(0, 0);  // w=0 pads
    const int m = min(64, end - j0);
    for (int q = 0; q < m; q += 8) {
      const int4 A = *(const int4*)&buf[wv][q];       // (d0,w0,d1,w1) broadcast read
      const int4 B = *(const int4*)&buf[wv][q + 2];
      const int4 C = *(const int4*)&buf[wv][q + 4];
      const int4 D = *(const int4*)&buf[wv][q + 6];
      const float e0 = bf2f(emb16[(size_t)A.x * OUT_DIM + lane]);
      const float e1 = bf2f(emb16[(size_t)A.z * OUT_DIM + lane]);
      const float e2 = bf2f(emb16[(size_t)B.x * OUT_DIM + lane]);
      const float e3 = bf2f(emb16[(size_t)B.z * OUT_DIM + lane]);
      const float e4 = bf2f(emb16[(size_t)C.x * OUT_DIM + lane]);
      const float e5 = bf2f(emb16[(size_t)C.z * OUT_DIM + lane]);
      const float e6 = bf2f(emb16[(size_t)D.x * OUT_DIM + lane]);
      const float e7 = bf2f(emb16[(size_t)D.z * OUT_DIM + lane]);
      const float w0 = __int_as_float(A.y), w1 = __int_as_float(A.w);
      const float w2 = __int_as_float(B.y), w3 = __int_as_float(B.w);
      const float w4 = __int_as_float(C.y), w5 = __int_as_float(C.w);
      const float w6 = __int_as_float(D.y), w7 = __int_as_float(D.w);
      acc0 += w0 * e0; acc1 += w1 * e1; acc2 += w2 * e2; acc3 += w3 * e3;
      acc0 += w4 * e4; acc1 += w5 * e5; acc2 += w6 * e6; acc3 += w7 * e7;
      ws0 += w0 + w1 + w2 + w3;
      ws1 += w4 + w5 + w6 + w7;
    }
  }
  out[(size_t)node * OUT_DIM + lane] = (acc0 + acc1 + acc2 + acc3) / (ws0 + ws1);
}

extern "C" void kernel_launch(void* const* d_in, const int* in_sizes, int n_in,
                              void* d_out, int out_size, void* d_ws, size_t ws_size,
                              hipStream_t stream) {
  const float* features = (const float*)d_in[0];
  const float* W        = (const float*)d_in[1];
  const float* b        = (const float*)d_in[2];
  const float* a        = (const float*)d_in[3];
  const int*   edges    = (const int*)d_in[4];
  float* out = (float*)d_out;

  // workspace layout (4B units)
  unsigned short* emb16 = (unsigned short*)d_ws;     // N*64 ushort = N*32 ints
  float* s1    = (float*)d_ws + (size_t)N_NODES * 32;  // N
  float* s2    = s1 + N_NODES;                       // N
  int*   off   = (int*)(s2 + N_NODES);               // N+1
  int*   bcnt  = off + N_NODES + 1;                  // NBKT
  int*   bbase = bcnt + NBKT;                        // NBKT+1
  int*   bcur  = bbase + NBKT + 1;                   // NBKT
  int*   flag  = bcur + NBKT;                        // 1 (+pad)
  int2*  pairs = (int2*)(flag + 8);                  // E (8B each)

  hipLaunchKernelGGL(zero_detect_kernel, dim3((NBKT + 255) / 256), dim3(256), 0, stream,
                     bcnt, edges, flag);
  hipLaunchKernelGGL(embed_kernel, dim3(NBKT), dim3(256), 0, stream,
                     features, W, b, a, emb16, s1, s2);
  hipLaunchKernelGGL(hist_kernel, dim3(HIST_GRID), dim3(256), 0, stream,
                     edges, flag, bcnt);
  hipLaunchKernelGGL(bucket_scan_kernel, dim3(1), dim3(1024), 0, stream,
                     bcnt, bbase, bcur);
  hipLaunchKernelGGL(bucket_scatter_kernel, dim3(SC_GRID), dim3(SC_BLOCK), 0, stream,
                     edges, bcur, pairs, flag);
  hipLaunchKernelGGL(bucket_sort_kernel, dim3(NBKT), dim3(256), 0, stream,
                     s1, s2, bbase, pairs, off);
  hipLaunchKernelGGL(aggregate_kernel, dim3((N_NODES + 3) / 4), dim3(256), 0, stream,
                     emb16, s1, s2, off, pairs, out);
}